// Round 3
// baseline (420.786 us; speedup 1.0000x reference)
//
#include <hip/hip_runtime.h>
#include <hip/hip_bf16.h>
#include <math.h>

// B=64, T=2048, H=512, Q=512
// energies[b,t] = enc[b,t,:] . v[b,:] + c[b]
//   v[b,h] = sum_q query[b,q] * W[q,h]   (W row-major [Q,H])
//   c[b]   = query[b,:] . bias
// softmax over t < len=tgt[b]+1; context[b,:] = sum_t p[b,t] * enc[b,t,:]
//
// Fused single-pass flash-style: enc read EXACTLY ONCE from HBM.
// k_attn: wave-per-row, TWO independent online-softmax chains per wave
// (even/odd rows) to double memory-level parallelism and halve the serial
// exp/alpha dependency chain. No LDS, no barriers in the hot kernel.

#define B 64
#define T 2048
#define H 512
#define Q 512
#define TT 64           // rows per block-chunk
#define NCH (T / TT)    // 32 chunks per batch
#define NPW (NCH * 4)   // 128 wave-partials per batch (4 waves/block)

// ---------------------------------------------------------------- kernel 1
// v[b,h], c[b].  grid (H/128, B), block 128.
__global__ void k_proj(const float* __restrict__ query,
                       const float* __restrict__ W,
                       const float* __restrict__ bias,
                       float* __restrict__ v,
                       float* __restrict__ c) {
    int b = blockIdx.y;
    int tid = threadIdx.x;           // 0..127
    int h = blockIdx.x * 128 + tid;

    __shared__ float sq[Q];
    for (int i = tid; i < Q; i += 128) sq[i] = query[(size_t)b * Q + i];
    __syncthreads();

    float acc = 0.0f;
#pragma unroll 8
    for (int q = 0; q < Q; ++q) acc += sq[q] * W[(size_t)q * H + h];
    v[(size_t)b * H + h] = acc;

    if (blockIdx.x == 0) {
        float pb = 0.0f;
        for (int i = tid; i < Q; i += 128) pb += sq[i] * bias[i];
        for (int off = 32; off; off >>= 1) pb += __shfl_xor(pb, off, 64);
        __shared__ float sred[2];
        if ((tid & 63) == 0) sred[tid >> 6] = pb;
        __syncthreads();
        if (tid == 0) c[b] = sred[0] + sred[1];
    }
}

// ---------------------------------------------------------------- kernel 2
// Fused energy + online-softmax + context partial. grid (NCH, B), block 256.
// Wave w owns rows {w, w+4, ..., w+60} of its 64-row chunk; chain A takes
// t = w+8j, chain B takes t = w+4+8j — independent until the final merge.
__global__ __launch_bounds__(256) void k_attn(const float* __restrict__ enc,
                                              const float* __restrict__ v,
                                              const float* __restrict__ c,
                                              const int* __restrict__ tgt,
                                              float* __restrict__ pm,
                                              float* __restrict__ pl,
                                              float* __restrict__ pctx) {
    int b = blockIdx.y;
    int len = tgt[b] + 1;
    int t0 = blockIdx.x * TT;
    if (t0 >= len) return;           // uniform exit
    int n = min(TT, len - t0);

    int tid = threadIdx.x;
    int wave = tid >> 6;
    int lane = tid & 63;

    const float4* v4 = (const float4*)(v + (size_t)b * H);
    float4 w0 = v4[lane];
    float4 w1 = v4[lane + 64];
    float cb = c[b];

    float mA = -INFINITY, lA = 0.0f;
    float mB = -INFINITY, lB = 0.0f;
    float4 a0 = {0.f,0.f,0.f,0.f}, a1 = {0.f,0.f,0.f,0.f};   // chain A ctx
    float4 b0 = {0.f,0.f,0.f,0.f}, b1 = {0.f,0.f,0.f,0.f};   // chain B ctx

    const float* encb = enc + (size_t)b * T * H;

    for (int t = wave; t < n; t += 8) {
        const float4* rowA = (const float4*)(encb + (size_t)(t0 + t) * H);
        float4 xa0 = rowA[lane];
        float4 xa1 = rowA[lane + 64];
        bool hasB = (t + 4) < n;                    // wave-uniform
        float4 xb0 = {0.f,0.f,0.f,0.f}, xb1 = {0.f,0.f,0.f,0.f};
        if (hasB) {
            const float4* rowB = (const float4*)(encb + (size_t)(t0 + t + 4) * H);
            xb0 = rowB[lane];
            xb1 = rowB[lane + 64];
        }

        float eA = xa0.x*w0.x + xa0.y*w0.y + xa0.z*w0.z + xa0.w*w0.w
                 + xa1.x*w1.x + xa1.y*w1.y + xa1.z*w1.z + xa1.w*w1.w;
        float eB = xb0.x*w0.x + xb0.y*w0.y + xb0.z*w0.z + xb0.w*w0.w
                 + xb1.x*w1.x + xb1.y*w1.y + xb1.z*w1.z + xb1.w*w1.w;
        // interleaved butterfly reduces (two independent chains)
        for (int off = 32; off; off >>= 1) {
            eA += __shfl_xor(eA, off, 64);
            eB += __shfl_xor(eB, off, 64);
        }
        eA += cb;
        eB += cb;

        {   // chain A update
            float mn = fmaxf(mA, eA);
            float alpha = __expf(mA - mn);
            float p = __expf(eA - mn);
            lA = lA * alpha + p;
            a0.x = a0.x*alpha + p*xa0.x;  a0.y = a0.y*alpha + p*xa0.y;
            a0.z = a0.z*alpha + p*xa0.z;  a0.w = a0.w*alpha + p*xa0.w;
            a1.x = a1.x*alpha + p*xa1.x;  a1.y = a1.y*alpha + p*xa1.y;
            a1.z = a1.z*alpha + p*xa1.z;  a1.w = a1.w*alpha + p*xa1.w;
            mA = mn;
        }
        if (hasB) {  // chain B update
            float mn = fmaxf(mB, eB);
            float alpha = __expf(mB - mn);
            float p = __expf(eB - mn);
            lB = lB * alpha + p;
            b0.x = b0.x*alpha + p*xb0.x;  b0.y = b0.y*alpha + p*xb0.y;
            b0.z = b0.z*alpha + p*xb0.z;  b0.w = b0.w*alpha + p*xb0.w;
            b1.x = b1.x*alpha + p*xb1.x;  b1.y = b1.y*alpha + p*xb1.y;
            b1.z = b1.z*alpha + p*xb1.z;  b1.w = b1.w*alpha + p*xb1.w;
            mB = mn;
        }
    }

    // merge chain B into chain A (guard the all-empty case: exp(-inf - -inf)=NaN)
    float mn = fmaxf(mA, mB);
    float aAl = (mA == -INFINITY) ? 0.0f : __expf(mA - mn);
    float aBl = (mB == -INFINITY) ? 0.0f : __expf(mB - mn);
    float lT = lA * aAl + lB * aBl;
    a0.x = a0.x*aAl + b0.x*aBl;  a0.y = a0.y*aAl + b0.y*aBl;
    a0.z = a0.z*aAl + b0.z*aBl;  a0.w = a0.w*aAl + b0.w*aBl;
    a1.x = a1.x*aAl + b1.x*aBl;  a1.y = a1.y*aAl + b1.y*aBl;
    a1.z = a1.z*aAl + b1.z*aBl;  a1.w = a1.w*aAl + b1.w*aBl;

    int pidx = (b * NCH + blockIdx.x) * 4 + wave;
    if (lane == 0) { pm[pidx] = mn; pl[pidx] = lT; }
    float4* dst = (float4*)(pctx + (size_t)pidx * H);
    dst[lane]      = a0;
    dst[lane + 64] = a1;
}

// ---------------------------------------------------------------- kernel 3
// Merge per-wave partials; write final out. grid (B), block 256.
__global__ void k_combine(const float* __restrict__ pm,
                          const float* __restrict__ pl,
                          const float* __restrict__ pctx,
                          const int* __restrict__ tgt,
                          float* __restrict__ out) {
    int b = blockIdx.x;
    int len = tgt[b] + 1;
    int nch = (len + TT - 1) / TT;
    int np = nch * 4;
    int base = b * NPW;
    int tid = threadIdx.x;

    float M = -INFINITY;
    for (int j = 0; j < np; ++j) M = fmaxf(M, pm[base + j]);
    float L = 0.0f;
    for (int j = 0; j < np; ++j) {
        float mj = pm[base + j];
        if (mj != -INFINITY) L += pl[base + j] * __expf(mj - M);
    }
    float invL = 1.0f / L;

    float acc0 = 0.0f, acc1 = 0.0f;
    for (int j = 0; j < np; ++j) {
        float mj = pm[base + j];
        float w = (mj == -INFINITY) ? 0.0f : __expf(mj - M) * invL;
        const float2* pc = (const float2*)(pctx + (size_t)(base + j) * H);
        float2 x = pc[tid];
        acc0 += w * x.x;
        acc1 += w * x.y;
    }
    out[(size_t)b * H + 2 * tid]     = acc0;
    out[(size_t)b * H + 2 * tid + 1] = acc1;
}

// ---------------------------------------------------------------- launch
extern "C" void kernel_launch(void* const* d_in, const int* in_sizes, int n_in,
                              void* d_out, int out_size, void* d_ws, size_t ws_size,
                              hipStream_t stream) {
    const float* query = (const float*)d_in[0];   // [B,Q]
    const float* enc   = (const float*)d_in[1];   // [B,T,H]
    const float* W     = (const float*)d_in[2];   // [Q,H]
    const float* bias  = (const float*)d_in[3];   // [Q]
    const int*   tgt   = (const int*)d_in[4];     // [B]
    float* out = (float*)d_out;                   // [B,H]

    char* ws = (char*)d_ws;
    float* v    = (float*)ws;  ws += (size_t)B * H * sizeof(float);
    float* c    = (float*)ws;  ws += 256;
    float* pm   = (float*)ws;  ws += (size_t)B * NPW * sizeof(float);
    float* pl   = (float*)ws;  ws += (size_t)B * NPW * sizeof(float);
    float* pctx = (float*)ws;  // B * NPW * H floats = 16 MB

    k_proj<<<dim3(H / 128, B), dim3(128), 0, stream>>>(query, W, bias, v, c);
    k_attn<<<dim3(NCH, B), dim3(256), 0, stream>>>(enc, v, c, tgt, pm, pl, pctx);
    k_combine<<<dim3(B), dim3(256), 0, stream>>>(pm, pl, pctx, tgt, out);
}

// Round 4
// 377.910 us; speedup vs baseline: 1.1135x; 1.1135x over previous
//
#include <hip/hip_runtime.h>
#include <hip/hip_bf16.h>
#include <math.h>

// B=64, T=2048, H=512, Q=512
// energies[b,t] = enc[b,t,:] . v[b,:] + c[b]
//   v[b,h] = sum_q query[b,q] * W[q,h]   (W row-major [Q,H])
//   c[b]   = query[b,:] . bias
// softmax over t < len=tgt[b]+1; context[b,:] = sum_t p[b,t] * enc[b,t,:]
//
// Single-pass flash-style, enc read EXACTLY ONCE.
// k_attn: wave processes rows in QUADS — 8 float4 loads in flight, 4
// interleaved butterfly reduces, ONE alpha-rescale per 4 rows. The 4 wave
// partials are merged in LDS -> one partial per block (pctx = 2 MB).

#define B 64
#define T 2048
#define H 512
#define Q 512
#define TT 128          // rows per block-chunk
#define NCH (T / TT)    // 16 chunks per batch

// ---------------------------------------------------------------- kernel 1
__global__ void k_proj(const float* __restrict__ query,
                       const float* __restrict__ W,
                       const float* __restrict__ bias,
                       float* __restrict__ v,
                       float* __restrict__ c) {
    int b = blockIdx.y;
    int tid = threadIdx.x;           // 0..127
    int h = blockIdx.x * 128 + tid;

    __shared__ float sq[Q];
    for (int i = tid; i < Q; i += 128) sq[i] = query[(size_t)b * Q + i];
    __syncthreads();

    float acc = 0.0f;
#pragma unroll 8
    for (int q = 0; q < Q; ++q) acc += sq[q] * W[(size_t)q * H + h];
    v[(size_t)b * H + h] = acc;

    if (blockIdx.x == 0) {
        float pb = 0.0f;
        for (int i = tid; i < Q; i += 128) pb += sq[i] * bias[i];
        for (int off = 32; off; off >>= 1) pb += __shfl_xor(pb, off, 64);
        __shared__ float sred[2];
        if ((tid & 63) == 0) sred[tid >> 6] = pb;
        __syncthreads();
        if (tid == 0) c[b] = sred[0] + sred[1];
    }
}

// ---------------------------------------------------------------- kernel 2
// grid (NCH, B), block 256 (4 waves). Wave w owns quads starting at
// t = 4w + 16j within its 128-row chunk.
__global__ __launch_bounds__(256) void k_attn(const float* __restrict__ enc,
                                              const float* __restrict__ v,
                                              const float* __restrict__ c,
                                              const int* __restrict__ tgt,
                                              float* __restrict__ pm,
                                              float* __restrict__ pl,
                                              float* __restrict__ pctx) {
    int b = blockIdx.y;
    int len = tgt[b] + 1;
    int t0 = blockIdx.x * TT;
    if (t0 >= len) return;           // uniform exit before any sync? no sync
                                     // until merge; all waves in block reach it
    int n = min(TT, len - t0);

    int tid = threadIdx.x;
    int wave = tid >> 6;
    int lane = tid & 63;

    const float4* v4 = (const float4*)(v + (size_t)b * H);
    float4 w0 = v4[lane];
    float4 w1 = v4[lane + 64];
    float cb = c[b];

    float m = -INFINITY, l = 0.0f;
    float4 a0 = {0.f,0.f,0.f,0.f}, a1 = {0.f,0.f,0.f,0.f};
    const float* encb = enc + ((size_t)b * T + t0) * H;

    for (int t = wave * 4; t < n; t += 16) {
        // quad rows t..t+3 — all in-bounds of the T-row buffer, masked below
        const float4* r0 = (const float4*)(encb + (size_t)(t + 0) * H);
        const float4* r1 = (const float4*)(encb + (size_t)(t + 1) * H);
        const float4* r2 = (const float4*)(encb + (size_t)(t + 2) * H);
        const float4* r3 = (const float4*)(encb + (size_t)(t + 3) * H);
        float4 x00 = r0[lane], x01 = r0[lane + 64];
        float4 x10 = r1[lane], x11 = r1[lane + 64];
        float4 x20 = r2[lane], x21 = r2[lane + 64];
        float4 x30 = r3[lane], x31 = r3[lane + 64];

        float e0 = x00.x*w0.x + x00.y*w0.y + x00.z*w0.z + x00.w*w0.w
                 + x01.x*w1.x + x01.y*w1.y + x01.z*w1.z + x01.w*w1.w;
        float e1 = x10.x*w0.x + x10.y*w0.y + x10.z*w0.z + x10.w*w0.w
                 + x11.x*w1.x + x11.y*w1.y + x11.z*w1.z + x11.w*w1.w;
        float e2 = x20.x*w0.x + x20.y*w0.y + x20.z*w0.z + x20.w*w0.w
                 + x21.x*w1.x + x21.y*w1.y + x21.z*w1.z + x21.w*w1.w;
        float e3 = x30.x*w0.x + x30.y*w0.y + x30.z*w0.z + x30.w*w0.w
                 + x31.x*w1.x + x31.y*w1.y + x31.z*w1.z + x31.w*w1.w;

        // 4 interleaved butterfly reduces — latency amortized 4x
        for (int off = 32; off; off >>= 1) {
            e0 += __shfl_xor(e0, off, 64);
            e1 += __shfl_xor(e1, off, 64);
            e2 += __shfl_xor(e2, off, 64);
            e3 += __shfl_xor(e3, off, 64);
        }
        // t+0 < n guaranteed by loop condition
        e0 += cb;
        e1 = (t + 1 < n) ? e1 + cb : -INFINITY;
        e2 = (t + 2 < n) ? e2 + cb : -INFINITY;
        e3 = (t + 3 < n) ? e3 + cb : -INFINITY;

        float mn = fmaxf(fmaxf(fmaxf(e0, e1), fmaxf(e2, e3)), m);
        // mn is finite (e0 finite), so no NaN guards needed:
        float alpha = __expf(m - mn);        // first iter: exp(-inf)=0
        float p0 = __expf(e0 - mn);
        float p1 = __expf(e1 - mn);          // masked rows -> 0
        float p2 = __expf(e2 - mn);
        float p3 = __expf(e3 - mn);
        l = l * alpha + (p0 + p1) + (p2 + p3);
        a0.x = a0.x*alpha + p0*x00.x + p1*x10.x + p2*x20.x + p3*x30.x;
        a0.y = a0.y*alpha + p0*x00.y + p1*x10.y + p2*x20.y + p3*x30.y;
        a0.z = a0.z*alpha + p0*x00.z + p1*x10.z + p2*x20.z + p3*x30.z;
        a0.w = a0.w*alpha + p0*x00.w + p1*x10.w + p2*x20.w + p3*x30.w;
        a1.x = a1.x*alpha + p0*x01.x + p1*x11.x + p2*x21.x + p3*x31.x;
        a1.y = a1.y*alpha + p0*x01.y + p1*x11.y + p2*x21.y + p3*x31.y;
        a1.z = a1.z*alpha + p0*x01.z + p1*x11.z + p2*x21.z + p3*x31.z;
        a1.w = a1.w*alpha + p0*x01.w + p1*x11.w + p2*x21.w + p3*x31.w;
        m = mn;
    }

    // ---- block-level merge of the 4 wave partials via LDS ----
    __shared__ float sm4[4], sl4[4];
    __shared__ float sctx[4 * H];            // 8 KB
    float4* sc = (float4*)(sctx + wave * H);
    sc[lane]      = a0;
    sc[lane + 64] = a1;
    if (lane == 0) { sm4[wave] = m; sl4[wave] = l; }
    __syncthreads();

    // thread tid merges h = {2*tid, 2*tid+1} across the 4 wave partials
    float M = fmaxf(fmaxf(sm4[0], sm4[1]), fmaxf(sm4[2], sm4[3]));  // finite
    float L = 0.0f, acc0 = 0.0f, acc1 = 0.0f;
#pragma unroll
    for (int j = 0; j < 4; ++j) {
        float mj = sm4[j];
        float wj = (mj == -INFINITY) ? 0.0f : __expf(mj - M);
        L += sl4[j] * wj;
        acc0 += wj * sctx[j * H + 2 * tid];
        acc1 += wj * sctx[j * H + 2 * tid + 1];
    }
    int pidx = b * NCH + blockIdx.x;
    if (tid == 0) { pm[pidx] = M; pl[pidx] = L; }
    float2* dst = (float2*)(pctx + (size_t)pidx * H);
    dst[tid] = make_float2(acc0, acc1);
}

// ---------------------------------------------------------------- kernel 3
// grid (B), block 256. nch <= 16 chunk partials per batch.
__global__ void k_combine(const float* __restrict__ pm,
                          const float* __restrict__ pl,
                          const float* __restrict__ pctx,
                          const int* __restrict__ tgt,
                          float* __restrict__ out) {
    int b = blockIdx.x;
    int tid = threadIdx.x;
    int len = tgt[b] + 1;
    int nch = (len + TT - 1) / TT;           // 1..16

    __shared__ float spm[NCH], spl[NCH];
    if (tid < nch) {
        spm[tid] = pm[b * NCH + tid];
        spl[tid] = pl[b * NCH + tid];
    }
    __syncthreads();

    float M = -INFINITY;
    for (int j = 0; j < nch; ++j) M = fmaxf(M, spm[j]);
    float L = 0.0f;
    for (int j = 0; j < nch; ++j) L += spl[j] * __expf(spm[j] - M);
    float invL = 1.0f / L;

    float acc0 = 0.0f, acc1 = 0.0f;
    for (int j = 0; j < nch; ++j) {
        float wj = __expf(spm[j] - M) * invL;
        float2 x = ((const float2*)(pctx + (size_t)(b * NCH + j) * H))[tid];
        acc0 += wj * x.x;
        acc1 += wj * x.y;
    }
    out[(size_t)b * H + 2 * tid]     = acc0;
    out[(size_t)b * H + 2 * tid + 1] = acc1;
}

// ---------------------------------------------------------------- launch
extern "C" void kernel_launch(void* const* d_in, const int* in_sizes, int n_in,
                              void* d_out, int out_size, void* d_ws, size_t ws_size,
                              hipStream_t stream) {
    const float* query = (const float*)d_in[0];   // [B,Q]
    const float* enc   = (const float*)d_in[1];   // [B,T,H]
    const float* W     = (const float*)d_in[2];   // [Q,H]
    const float* bias  = (const float*)d_in[3];   // [Q]
    const int*   tgt   = (const int*)d_in[4];     // [B]
    float* out = (float*)d_out;                   // [B,H]

    char* ws = (char*)d_ws;
    float* v    = (float*)ws;  ws += (size_t)B * H * sizeof(float);
    float* c    = (float*)ws;  ws += 256;
    float* pm   = (float*)ws;  ws += (size_t)B * NCH * sizeof(float);
    float* pl   = (float*)ws;  ws += (size_t)B * NCH * sizeof(float);
    float* pctx = (float*)ws;  // B * NCH * H floats = 2 MB

    k_proj<<<dim3(H / 128, B), dim3(128), 0, stream>>>(query, W, bias, v, c);
    k_attn<<<dim3(NCH, B), dim3(256), 0, stream>>>(enc, v, c, tgt, pm, pl, pctx);
    k_combine<<<dim3(B), dim3(256), 0, stream>>>(pm, pl, pctx, tgt, out);
}